// Round 4
// baseline (4000.721 us; speedup 1.0000x reference)
//
#include <hip/hip_runtime.h>

#define H 128
#define FN 16
#define FE 8
#define NBUK_MAX 1600   // buckets = ceil(N/64) = 1563 for N=100k

// ============================ histogram (both sorts) + gbounds fused ============================
// blocks [0,512): histogram.  blocks [512, 512+gbB): graph-boundary scan (independent work).
__global__ __launch_bounds__(256) void k_hist2_gb(
    const int* __restrict__ k1, const int* __restrict__ k2,
    int* __restrict__ bcnt1, int* __restrict__ bcnt2, int E, int nbuk,
    const int* __restrict__ batch, int* __restrict__ gstart, int N, int G) {
  if (blockIdx.x >= 512) {
    int n = (blockIdx.x - 512) * 256 + threadIdx.x;
    if (n > N) return;
    if (n == 0) {
      for (int g = 0; g <= batch[0]; g++) gstart[g] = 0;
    } else if (n == N) {
      for (int g = batch[N - 1] + 1; g <= G; g++) gstart[g] = N;
    } else {
      int b0 = batch[n - 1], b1 = batch[n];
      for (int g = b0 + 1; g <= b1; g++) gstart[g] = n;
    }
    return;
  }
  __shared__ int h1[NBUK_MAX], h2[NBUK_MAX];
  for (int i = threadIdx.x; i < nbuk; i += 256) { h1[i] = 0; h2[i] = 0; }
  __syncthreads();
  for (int e = blockIdx.x * 256 + threadIdx.x; e < E; e += 512 * 256) {
    atomicAdd(&h1[k1[e] >> 6], 1);
    atomicAdd(&h2[k2[e] >> 6], 1);
  }
  __syncthreads();
  for (int i = threadIdx.x; i < nbuk; i += 256) {
    if (h1[i]) atomicAdd(&bcnt1[i], h1[i]);
    if (h2[i]) atomicAdd(&bcnt2[i], h2[i]);
  }
}

// ============================ single-block dual scan ============================
__global__ __launch_bounds__(1024) void k_scan(
    const int* __restrict__ cnt1, int* __restrict__ st1, int* __restrict__ gc1,
    const int* __restrict__ cnt2, int* __restrict__ st2, int* __restrict__ gc2,
    int nbuk) {
  __shared__ int s[1024];
  int tid = threadIdx.x;
  for (int pass = 0; pass < 2; pass++) {
    const int* cnt = pass ? cnt2 : cnt1;
    int* st = pass ? st2 : st1;
    int* gc = pass ? gc2 : gc1;
    int run = 0;
    for (int half = 0; half * 1024 < nbuk; half++) {
      int i = half * 1024 + tid;
      int v = (i < nbuk) ? cnt[i] : 0;
      s[tid] = v; __syncthreads();
      for (int off = 1; off < 1024; off <<= 1) {
        int t = (tid >= off) ? s[tid - off] : 0;
        __syncthreads();
        s[tid] += t;
        __syncthreads();
      }
      int excl = run + s[tid] - v;
      if (i < nbuk) { st[i] = excl; gc[i] = excl; }
      run += s[1023];
      __syncthreads();
    }
    if (tid == 0) st[nbuk] = run;
    __syncthreads();
  }
}

// ============================ pass-1 bucket scatter: BOTH sorts in one launch ============================
// blocks [0,p1b): packed-key sort of edge dsts.  blocks [p1b,2*p1b): payload sort of adjacency.
__global__ __launch_bounds__(256) void k_p1_both(
    const int* __restrict__ k1, const int* __restrict__ adj, const float* __restrict__ vals,
    int* __restrict__ gcur1, int* __restrict__ gcur2,
    int* __restrict__ pkey, int2* __restrict__ bpay, int E, int nbuk, int p1b) {
  __shared__ int hc[NBUK_MAX];
  int tid = threadIdx.x;
  bool packed = (int)blockIdx.x < p1b;
  int chunk = packed ? blockIdx.x : blockIdx.x - p1b;
  const int* key = packed ? k1 : adj;     // adj[0..E) = src keys
  int* gcur = packed ? gcur1 : gcur2;
  int c0 = chunk * 8192;
  int c1 = min(c0 + 8192, E);
  for (int i = tid; i < nbuk; i += 256) hc[i] = 0;
  __syncthreads();
  for (int e = c0 + tid; e < c1; e += 256)
    atomicAdd(&hc[key[e] >> 6], 1);
  __syncthreads();
  for (int i = tid; i < nbuk; i += 256) {
    int c = hc[i];
    if (c) hc[i] = atomicAdd(&gcur[i], c);
  }
  __syncthreads();
  if (packed) {
    for (int e = c0 + tid; e < c1; e += 256) {
      int k = key[e];
      int pos = atomicAdd(&hc[k >> 6], 1);
      pkey[pos] = (e << 6) | (k & 63);
    }
  } else {
    const int* dsts = adj + E;
    for (int e = c0 + tid; e < c1; e += 256) {
      int k = key[e];
      int pos = atomicAdd(&hc[k >> 6], 1);
      bpay[pos] = make_int2(dsts[e] | ((k & 63) << 20), __float_as_int(vals[e]));
    }
  }
}

// ============================ embed agg + h compute | adj pass-2 (dst-bucket sort), fused ============================
// blocks [0,nbuk): edge-attr aggregation -> h = relu(na@Wn + agg@We + b) directly.
// blocks [nbuk,2*nbuk): within-src-bucket counting sort of adjacency by DST-BUCKET (dst>>6)
//   (+rowsum). The dst-sorted order makes every k_fused block sweep h[] low->high so
//   co-resident blocks' gathers share an L2 window instead of random-missing over 51 MB.
__global__ __launch_bounds__(256) void k_agg_p2(
    const int* __restrict__ pkey, const float* __restrict__ edge_attr,
    const int* __restrict__ bst1,
    const float* __restrict__ node_attr, const float* __restrict__ Wn,
    const float* __restrict__ We8, const float* __restrict__ bemb,
    float* __restrict__ hout,
    const int2* __restrict__ bpay, const int* __restrict__ bst2,
    int2* __restrict__ payF, float* __restrict__ rs,
    int N, int E, int nbuk) {
  __shared__ float lds[FE][64];
  __shared__ float na[64][FN];
  __shared__ int hist[NBUK_MAX];
  __shared__ int psum[256];
  __shared__ float vsum[64];
  int tid = threadIdx.x;

  if ((int)blockIdx.x < nbuk) {
    // ---- embed aggregation + h ----
    int b = blockIdx.x;
    int node0 = b * 64;
    int col = tid & 127;
    int half = tid >> 7;
    float wreg[FN + FE];
#pragma unroll
    for (int k = 0; k < FN; k++) wreg[k] = Wn[k * H + col];
#pragma unroll
    for (int k = 0; k < FE; k++) wreg[FN + k] = We8[k * H + col];
    float bcol = bemb[col];

    for (int i = tid; i < FE * 64; i += 256) ((float*)lds)[i] = 0.f;
    for (int i = tid; i < 64 * FN; i += 256) {
      int n = node0 + (i >> 4);
      na[i >> 4][i & 15] = (n < N) ? node_attr[(size_t)n * FN + (i & 15)] : 0.f;
    }
    __syncthreads();
    int s = bst1[b], t = bst1[b + 1];
    int i = s + tid;
    for (; i + 256 < t; i += 512) {
      int pk0 = pkey[i], pk1 = pkey[i + 256];
      const float4* e0 = (const float4*)(edge_attr + (size_t)(pk0 >> 6) * FE);
      const float4* e1 = (const float4*)(edge_attr + (size_t)(pk1 >> 6) * FE);
      float4 a0 = e0[0], b0 = e0[1], a1 = e1[0], b1 = e1[1];
      int s0 = pk0 & 63, s1 = pk1 & 63;
      atomicAdd(&lds[0][s0], a0.x);  atomicAdd(&lds[1][s0], a0.y);
      atomicAdd(&lds[2][s0], a0.z);  atomicAdd(&lds[3][s0], a0.w);
      atomicAdd(&lds[4][s0], b0.x);  atomicAdd(&lds[5][s0], b0.y);
      atomicAdd(&lds[6][s0], b0.z);  atomicAdd(&lds[7][s0], b0.w);
      atomicAdd(&lds[0][s1], a1.x);  atomicAdd(&lds[1][s1], a1.y);
      atomicAdd(&lds[2][s1], a1.z);  atomicAdd(&lds[3][s1], a1.w);
      atomicAdd(&lds[4][s1], b1.x);  atomicAdd(&lds[5][s1], b1.y);
      atomicAdd(&lds[6][s1], b1.z);  atomicAdd(&lds[7][s1], b1.w);
    }
    for (; i < t; i += 256) {
      int pk = pkey[i];
      int e = pk >> 6, slot = pk & 63;
      const float4* ea = (const float4*)(edge_attr + (size_t)e * FE);
      float4 a = ea[0], b4 = ea[1];
      atomicAdd(&lds[0][slot], a.x);  atomicAdd(&lds[1][slot], a.y);
      atomicAdd(&lds[2][slot], a.z);  atomicAdd(&lds[3][slot], a.w);
      atomicAdd(&lds[4][slot], b4.x); atomicAdd(&lds[5][slot], b4.y);
      atomicAdd(&lds[6][slot], b4.z); atomicAdd(&lds[7][slot], b4.w);
    }
    __syncthreads();
    for (int pr = 0; pr < 32; pr++) {
      int nl = pr * 2 + half;
      int n = node0 + nl;
      float acc = bcol;
#pragma unroll
      for (int k = 0; k < FN; k++) acc += na[nl][k] * wreg[k];
#pragma unroll
      for (int k = 0; k < FE; k++) acc += lds[k][nl] * wreg[FN + k];
      if (n < N) hout[(size_t)n * H + col] = fmaxf(acc, 0.f);
    }
  } else {
    // ---- adjacency pass-2: counting sort by dst-bucket within src-bucket (+rs) ----
    int b = blockIdx.x - nbuk;
    int s = bst2[b], t = bst2[b + 1];
    for (int i = tid; i < nbuk; i += 256) hist[i] = 0;
    if (tid < 64) vsum[tid] = 0.f;
    __syncthreads();
    for (int i = s + tid; i < t; i += 256) {
      int2 p = bpay[i];
      atomicAdd(&hist[(p.x & 0xFFFFF) >> 6], 1);
      atomicAdd(&vsum[(p.x >> 20) & 63], __int_as_float(p.y));
    }
    __syncthreads();
    // blocked exclusive scan of hist[0..nbuk): thread owns 7 entries (7*256=1792>=1600)
    int bse = tid * 7;
    int lsum = 0;
#pragma unroll
    for (int j = 0; j < 7; j++) { int idx = bse + j; lsum += (idx < nbuk) ? hist[idx] : 0; }
    psum[tid] = lsum;
    __syncthreads();
    for (int off = 1; off < 256; off <<= 1) {
      int v = (tid >= off) ? psum[tid - off] : 0;
      __syncthreads();
      psum[tid] += v;
      __syncthreads();
    }
    int run = s + psum[tid] - lsum;
#pragma unroll
    for (int j = 0; j < 7; j++) {
      int idx = bse + j;
      if (idx < nbuk) { int cv = hist[idx]; hist[idx] = run; run += cv; }
    }
    __syncthreads();
    for (int i = s + tid; i < t; i += 256) {
      int2 p = bpay[i];
      int pos = atomicAdd(&hist[(p.x & 0xFFFFF) >> 6], 1);
      payF[pos] = p;    // keep slot bits 20-25 + dst bits 0-19 + val
    }
    if (tid < 64) {
      int node = b * 64 + tid;
      if (node < N) rs[node] = vsum[tid];
    }
  }
}

// ============================ fused GCN layer (dst-sweep) ============================
// out[n] = relu( (sum val*h[dst]) @ W + rs[n]*b )
// v5: block = one 64-node src bucket; edges pre-sorted by dst-bucket, so the
// gather stream sweeps h[] low->high. Phase 1 streams edges round-robin over
// 8 groups, scatter-accumulating val*h[dst] into a 32 KB LDS accumulator via
// LDS float atomics. Layout acc_s[j][slot][c] puts bank = lane -> conflict-free
// ds_add. No per-row offs needed; no launch_bounds min-waves (spill lesson).
__global__ __launch_bounds__(256) void k_fused(
    const float* __restrict__ h, const int* __restrict__ ebnd,
    const int2* __restrict__ pay, const float* __restrict__ W,
    const float* __restrict__ bias, const float* __restrict__ rs,
    float* __restrict__ out, int N) {
  __shared__ float acc_s[4][64][32];   // 32 KB; acc_s[j][slot][c] = feature 4c+j of slot
  int tid = threadIdx.x;
  int c  = tid & 31;
  int g  = tid >> 5;                   // 8 groups of 32 lanes
  int b  = blockIdx.x;
  int base = b * 64;
  const float4* h4 = (const float4*)h;

  for (int i = tid; i < 4 * 64 * 32; i += 256) ((float*)acc_s)[i] = 0.f;
  __syncthreads();

  // ---- phase 1: streamed scatter-accumulate over dst-sorted bucket edges ----
  int s = ebnd[b], t = ebnd[b + 1];
  int nfull = (t - s) & ~31;           // 32 edges per block-iter (4 per group)
  for (int i = s + g * 4; i < s + nfull; i += 32) {
    int2 p0 = pay[i], p1 = pay[i + 1], p2 = pay[i + 2], p3 = pay[i + 3];
    float4 h0 = h4[(size_t)(p0.x & 0xFFFFF) * 32 + c];
    float4 h1 = h4[(size_t)(p1.x & 0xFFFFF) * 32 + c];
    float4 h2 = h4[(size_t)(p2.x & 0xFFFFF) * 32 + c];
    float4 h3 = h4[(size_t)(p3.x & 0xFFFFF) * 32 + c];
    float v0 = __int_as_float(p0.y), v1 = __int_as_float(p1.y);
    float v2 = __int_as_float(p2.y), v3 = __int_as_float(p3.y);
    int s0 = (p0.x >> 20) & 63, s1 = (p1.x >> 20) & 63;
    int s2 = (p2.x >> 20) & 63, s3 = (p3.x >> 20) & 63;
    atomicAdd(&acc_s[0][s0][c], v0 * h0.x);
    atomicAdd(&acc_s[1][s0][c], v0 * h0.y);
    atomicAdd(&acc_s[2][s0][c], v0 * h0.z);
    atomicAdd(&acc_s[3][s0][c], v0 * h0.w);
    atomicAdd(&acc_s[0][s1][c], v1 * h1.x);
    atomicAdd(&acc_s[1][s1][c], v1 * h1.y);
    atomicAdd(&acc_s[2][s1][c], v1 * h1.z);
    atomicAdd(&acc_s[3][s1][c], v1 * h1.w);
    atomicAdd(&acc_s[0][s2][c], v2 * h2.x);
    atomicAdd(&acc_s[1][s2][c], v2 * h2.y);
    atomicAdd(&acc_s[2][s2][c], v2 * h2.z);
    atomicAdd(&acc_s[3][s2][c], v2 * h2.w);
    atomicAdd(&acc_s[0][s3][c], v3 * h3.x);
    atomicAdd(&acc_s[1][s3][c], v3 * h3.y);
    atomicAdd(&acc_s[2][s3][c], v3 * h3.z);
    atomicAdd(&acc_s[3][s3][c], v3 * h3.w);
  }
  for (int i = s + nfull + g; i < t; i += 8) {
    int2 p = pay[i];
    float4 hv = h4[(size_t)(p.x & 0xFFFFF) * 32 + c];
    float v = __int_as_float(p.y);
    int sl = (p.x >> 20) & 63;
    atomicAdd(&acc_s[0][sl][c], v * hv.x);
    atomicAdd(&acc_s[1][sl][c], v * hv.y);
    atomicAdd(&acc_s[2][sl][c], v * hv.z);
    atomicAdd(&acc_s[3][sl][c], v * hv.w);
  }
  __syncthreads();

  // ---- phase 2: GEMM from LDS accumulator; W coalesced from global (L2-hot) ----
  const float4* W4 = (const float4*)W;   // [128][32]
  float4 acc[8];
#pragma unroll
  for (int i = 0; i < 8; i++) acc[i] = make_float4(0.f, 0.f, 0.f, 0.f);
#pragma unroll 2
  for (int k = 0; k < 32; k++) {
    float4 w0 = W4[(k * 4 + 0) * 32 + c];
    float4 w1 = W4[(k * 4 + 1) * 32 + c];
    float4 w2 = W4[(k * 4 + 2) * 32 + c];
    float4 w3 = W4[(k * 4 + 3) * 32 + c];
#pragma unroll
    for (int i = 0; i < 8; i++) {
      int row = g + 8 * i;               // group-uniform broadcast reads
      float hx = acc_s[0][row][k];
      float hy = acc_s[1][row][k];
      float hz = acc_s[2][row][k];
      float hw = acc_s[3][row][k];
      acc[i].x += hx * w0.x + hy * w1.x + hz * w2.x + hw * w3.x;
      acc[i].y += hx * w0.y + hy * w1.y + hz * w2.y + hw * w3.y;
      acc[i].z += hx * w0.z + hy * w1.z + hz * w2.z + hw * w3.z;
      acc[i].w += hx * w0.w + hy * w1.w + hz * w2.w + hw * w3.w;
    }
  }

  float4 bv = ((const float4*)bias)[c];
#pragma unroll
  for (int i = 0; i < 8; i++) {
    int row = g + 8 * i;
    int n = base + row;
    if (n < N) {
      float rsv = rs[n];
      float4 o;
      o.x = fmaxf(acc[i].x + rsv * bv.x, 0.f);
      o.y = fmaxf(acc[i].y + rsv * bv.y, 0.f);
      o.z = fmaxf(acc[i].z + rsv * bv.z, 0.f);
      o.w = fmaxf(acc[i].w + rsv * bv.w, 0.f);
      ((float4*)out)[(size_t)n * 32 + c] = o;
    }
  }
}

// ============================ predictor GEMM with fused final dot ============================
__global__ __launch_bounds__(256) void k_gemm_pred(
    const float* __restrict__ in, const float* __restrict__ W,
    const float* __restrict__ bias, const float* __restrict__ Wp2,
    const float* __restrict__ bp2, float* __restrict__ out, int N) {
  __shared__ float4 hs4[64 * 32];
  int tid = threadIdx.x;
  int c  = tid & 31;
  int rg = tid >> 5;
  int rowBase = blockIdx.x * 64;
  const float4* in4 = (const float4*)in;
  const float4* W4  = (const float4*)W;
#pragma unroll
  for (int j = 0; j < 8; j++) {
    int q = tid + 256 * j;
    int r = rowBase + (q >> 5);
    int rr = (r < N) ? r : (N - 1);
    hs4[q] = in4[(size_t)rr * 32 + (q & 31)];
  }
  __syncthreads();
  float4 acc[8];
#pragma unroll
  for (int i = 0; i < 8; i++) acc[i] = make_float4(0.f, 0.f, 0.f, 0.f);
#pragma unroll 2
  for (int k = 0; k < 32; k++) {
    float4 w0 = W4[(k * 4 + 0) * 32 + c];
    float4 w1 = W4[(k * 4 + 1) * 32 + c];
    float4 w2 = W4[(k * 4 + 2) * 32 + c];
    float4 w3 = W4[(k * 4 + 3) * 32 + c];
#pragma unroll
    for (int i = 0; i < 8; i++) {
      float4 hv = hs4[(rg + 8 * i) * 32 + k];
      acc[i].x += hv.x * w0.x + hv.y * w1.x + hv.z * w2.x + hv.w * w3.x;
      acc[i].y += hv.x * w0.y + hv.y * w1.y + hv.z * w2.y + hv.w * w3.y;
      acc[i].z += hv.x * w0.z + hv.y * w1.z + hv.z * w2.z + hv.w * w3.z;
      acc[i].w += hv.x * w0.w + hv.y * w1.w + hv.z * w2.w + hv.w * w3.w;
    }
  }
  float4 bv = ((const float4*)bias)[c];
  float4 wp = ((const float4*)Wp2)[c];
  float bp = bp2[0];
#pragma unroll
  for (int i = 0; i < 8; i++) {
    int row = rowBase + rg + 8 * i;
    float4 o;
    o.x = fmaxf(acc[i].x + bv.x, 0.f);
    o.y = fmaxf(acc[i].y + bv.y, 0.f);
    o.z = fmaxf(acc[i].z + bv.z, 0.f);
    o.w = fmaxf(acc[i].w + bv.w, 0.f);
    float v = o.x * wp.x + o.y * wp.y + o.z * wp.z + o.w * wp.w;
#pragma unroll
    for (int off = 16; off > 0; off >>= 1) v += __shfl_down(v, off, 32);
    if (c == 0 && row < N) out[row] = v + bp;
  }
}

// ============================ pool: 8-way node-parallel per graph ============================
__global__ __launch_bounds__(256) void k_pool_seg(
    const float* __restrict__ h, const int* __restrict__ gstart,
    float* __restrict__ fp, int G) {
  __shared__ float4 red[8][32];
  int g = blockIdx.x;
  int c = threadIdx.x & 31, rg = threadIdx.x >> 5;
  int s = gstart[g], t = gstart[g + 1];
  const float4* h4 = (const float4*)h;
  float4 a = make_float4(0.f, 0.f, 0.f, 0.f);
  for (int n = s + rg; n < t; n += 8) {
    float4 v = h4[(size_t)n * 32 + c];
    a.x += v.x; a.y += v.y; a.z += v.z; a.w += v.w;
  }
  red[rg][c] = a;
  __syncthreads();
  if (rg == 0) {
    float4 r = red[0][c];
#pragma unroll
    for (int j = 1; j < 8; j++) {
      float4 v = red[j][c];
      r.x += v.x; r.y += v.y; r.z += v.z; r.w += v.w;
    }
    ((float4*)fp)[(size_t)g * 32 + c] = r;
  }
}

// ============================ launch ============================
extern "C" void kernel_launch(void* const* d_in, const int* in_sizes, int n_in,
                              void* d_out, int out_size, void* d_ws, size_t ws_size,
                              hipStream_t stream) {
  const float* node_attr  = (const float*)d_in[0];
  const float* edge_attr  = (const float*)d_in[1];
  const int*   edge_index = (const int*)d_in[2];
  const int*   adj_index  = (const int*)d_in[3];
  const float* adj_value  = (const float*)d_in[4];
  const int*   batch      = (const int*)d_in[5];
  const float* W_node  = (const float*)d_in[6];
  const float* W_edge  = (const float*)d_in[7];
  const float* b_embed = (const float*)d_in[8];
  const float* W1 = (const float*)d_in[9];
  const float* b1 = (const float*)d_in[10];
  const float* W2 = (const float*)d_in[11];
  const float* b2 = (const float*)d_in[12];
  const float* W3 = (const float*)d_in[13];
  const float* b3 = (const float*)d_in[14];
  const float* Wp1 = (const float*)d_in[15];
  const float* bp1 = (const float*)d_in[16];
  const float* Wp2 = (const float*)d_in[17];
  const float* bp2 = (const float*)d_in[18];
  float* out = (float*)d_out;

  const int E = in_sizes[4];           // 1,600,000
  const int N = in_sizes[5];           // 100,000
  const int G = out_size;              // 2048
  const int nbuk = (N + 63) >> 6;      // 1563
  const int p1b = (E + 8191) / 8192;
  const int gbB = (N + 256) / 256;

  // ---- workspace layout ----
  float* A     = (float*)d_ws;                       // N*H
  float* B     = A + (size_t)N * H;                  // N*H
  int2*  payF  = (int2*)(B + (size_t)N * H);         // E
  float* fpool = (float*)(payF + E);                 // G*H
  int*   bcnt1 = (int*)(fpool + (size_t)G * H);      // nbuk  } one memset
  int*   bcnt2 = bcnt1 + nbuk;                       // nbuk  }
  int*   bst1  = bcnt2 + nbuk;                       // nbuk+1
  int*   gcur1 = bst1 + nbuk + 1;                    // nbuk
  int*   bst2  = gcur1 + nbuk;                       // nbuk+1
  int*   gcur2 = bst2 + nbuk + 1;                    // nbuk
  int*   gstart= gcur2 + nbuk;                       // G+1
  float* rs    = (float*)(gstart + G + 1);           // N
  // transient aliases (lifetimes by launch order):
  int*   pkey  = (int*)B;                            // E ints; dead after agg_p2
  int2*  bpay2 = (int2*)(((int*)B) + E);             // E int2; dead after agg_p2
  // h lives in A (agg_p2 reads pkey/bpay2 from B while writing h -> must not alias B)

  // ---- histograms (+graph bounds) + scans ----
  hipMemsetAsync(bcnt1, 0, (size_t)2 * nbuk * sizeof(int), stream);
  k_hist2_gb<<<512 + gbB, 256, 0, stream>>>(edge_index + E, adj_index, bcnt1, bcnt2,
                                            E, nbuk, batch, gstart, N, G);
  k_scan<<<1, 1024, 0, stream>>>(bcnt1, bst1, gcur1, bcnt2, bst2, gcur2, nbuk);

  // ---- both pass-1 scatters in one launch ----
  k_p1_both<<<2 * p1b, 256, 0, stream>>>(edge_index + E, adj_index, adj_value,
                                         gcur1, gcur2, pkey, bpay2, E, nbuk, p1b);

  // ---- embed agg + h compute | adj dst-bucket sort, one launch; h -> A ----
  k_agg_p2<<<2 * nbuk, 256, 0, stream>>>(pkey, edge_attr, bst1,
                                         node_attr, W_node, W_edge, b_embed, A,
                                         bpay2, bst2, payF, rs, N, E, nbuk);

  // ---- 3 fused GCN layers: out = relu(gather(in)@W + rs*b) ----
  k_fused<<<nbuk, 256, 0, stream>>>(A, bst2, payF, W1, b1, rs, B, N);
  k_fused<<<nbuk, 256, 0, stream>>>(B, bst2, payF, W2, b2, rs, A, N);
  k_fused<<<nbuk, 256, 0, stream>>>(A, bst2, payF, W3, b3, rs, B, N);

  // ---- pool + predictor (final dot fused into the GEMM) ----
  k_pool_seg<<<G, 256, 0, stream>>>(B, gstart, fpool, G);
  k_gemm_pred<<<(G + 63) / 64, 256, 0, stream>>>(fpool, Wp1, bp1, Wp2, bp2, out, G);
}

// Round 5
// 856.345 us; speedup vs baseline: 4.6719x; 4.6719x over previous
//
#include <hip/hip_runtime.h>

#define H 128
#define FN 16
#define FE 8
#define NBUK_MAX 1600   // buckets = ceil(N/64) = 1563 for N=100k

// ============================ histogram (both sorts) ============================
__global__ __launch_bounds__(256) void k_hist2(
    const int* __restrict__ k1, const int* __restrict__ k2,
    int* __restrict__ bcnt1, int* __restrict__ bcnt2, int E, int nbuk) {
  __shared__ int h1[NBUK_MAX], h2[NBUK_MAX];
  for (int i = threadIdx.x; i < nbuk; i += 256) { h1[i] = 0; h2[i] = 0; }
  __syncthreads();
  for (int e = blockIdx.x * 256 + threadIdx.x; e < E; e += 512 * 256) {
    atomicAdd(&h1[k1[e] >> 6], 1);
    atomicAdd(&h2[k2[e] >> 6], 1);
  }
  __syncthreads();
  for (int i = threadIdx.x; i < nbuk; i += 256) {
    if (h1[i]) atomicAdd(&bcnt1[i], h1[i]);
    if (h2[i]) atomicAdd(&bcnt2[i], h2[i]);
  }
}

// ============================ single-block dual scan ============================
__global__ __launch_bounds__(1024) void k_scan(
    const int* __restrict__ cnt1, int* __restrict__ st1, int* __restrict__ gc1,
    const int* __restrict__ cnt2, int* __restrict__ st2, int* __restrict__ gc2,
    int nbuk) {
  __shared__ int s[1024];
  int tid = threadIdx.x;
  for (int pass = 0; pass < 2; pass++) {
    const int* cnt = pass ? cnt2 : cnt1;
    int* st = pass ? st2 : st1;
    int* gc = pass ? gc2 : gc1;
    int run = 0;
    for (int half = 0; half * 1024 < nbuk; half++) {
      int i = half * 1024 + tid;
      int v = (i < nbuk) ? cnt[i] : 0;
      s[tid] = v; __syncthreads();
      for (int off = 1; off < 1024; off <<= 1) {
        int t = (tid >= off) ? s[tid - off] : 0;
        __syncthreads();
        s[tid] += t;
        __syncthreads();
      }
      int excl = run + s[tid] - v;
      if (i < nbuk) { st[i] = excl; gc[i] = excl; }
      run += s[1023];
      __syncthreads();
    }
    if (tid == 0) st[nbuk] = run;
    __syncthreads();
  }
}

// ============================ pass-1 bucket scatter: BOTH sorts in one launch ============================
__global__ __launch_bounds__(256) void k_p1_both(
    const int* __restrict__ k1, const int* __restrict__ adj, const float* __restrict__ vals,
    int* __restrict__ gcur1, int* __restrict__ gcur2,
    int* __restrict__ pkey, int2* __restrict__ bpay, int E, int nbuk, int p1b) {
  __shared__ int hc[NBUK_MAX];
  int tid = threadIdx.x;
  bool packed = (int)blockIdx.x < p1b;
  int chunk = packed ? blockIdx.x : blockIdx.x - p1b;
  const int* key = packed ? k1 : adj;     // adj[0..E) = src keys
  int* gcur = packed ? gcur1 : gcur2;
  int c0 = chunk * 8192;
  int c1 = min(c0 + 8192, E);
  for (int i = tid; i < nbuk; i += 256) hc[i] = 0;
  __syncthreads();
  for (int e = c0 + tid; e < c1; e += 256)
    atomicAdd(&hc[key[e] >> 6], 1);
  __syncthreads();
  for (int i = tid; i < nbuk; i += 256) {
    int c = hc[i];
    if (c) hc[i] = atomicAdd(&gcur[i], c);
  }
  __syncthreads();
  if (packed) {
    for (int e = c0 + tid; e < c1; e += 256) {
      int k = key[e];
      int pos = atomicAdd(&hc[k >> 6], 1);
      pkey[pos] = (e << 6) | (k & 63);
    }
  } else {
    const int* dsts = adj + E;
    for (int e = c0 + tid; e < c1; e += 256) {
      int k = key[e];
      int pos = atomicAdd(&hc[k >> 6], 1);
      bpay[pos] = make_int2(dsts[e] | ((k & 63) << 20), __float_as_int(vals[e]));
    }
  }
}

// ============================ embed agg + h compute | adj pass-2 (slot sort), fused ============================
// blocks [0,nbuk): edge-attr aggregation -> h = relu(na@Wn + agg@We + b) directly.
// blocks [nbuk,2*nbuk): adjacency pass-2 (emits offs, payF, rs).
__global__ __launch_bounds__(256) void k_agg_p2(
    const int* __restrict__ pkey, const float* __restrict__ edge_attr,
    const int* __restrict__ bst1,
    const float* __restrict__ node_attr, const float* __restrict__ Wn,
    const float* __restrict__ We8, const float* __restrict__ bemb,
    float* __restrict__ hout,
    const int2* __restrict__ bpay, const int* __restrict__ bst2,
    int* __restrict__ offs, int2* __restrict__ payF, float* __restrict__ rs,
    int N, int E, int nbuk) {
  __shared__ float lds[FE][64];
  __shared__ float na[64][FN];
  __shared__ int cnt[64], scn[64], cur[64];
  __shared__ float vsum[64];
  int tid = threadIdx.x;

  if ((int)blockIdx.x < nbuk) {
    // ---- embed aggregation + h ----
    int b = blockIdx.x;
    int node0 = b * 64;
    int col = tid & 127;
    int half = tid >> 7;
    float wreg[FN + FE];
#pragma unroll
    for (int k = 0; k < FN; k++) wreg[k] = Wn[k * H + col];
#pragma unroll
    for (int k = 0; k < FE; k++) wreg[FN + k] = We8[k * H + col];
    float bcol = bemb[col];

    for (int i = tid; i < FE * 64; i += 256) ((float*)lds)[i] = 0.f;
    for (int i = tid; i < 64 * FN; i += 256) {
      int n = node0 + (i >> 4);
      na[i >> 4][i & 15] = (n < N) ? node_attr[(size_t)n * FN + (i & 15)] : 0.f;
    }
    __syncthreads();
    int s = bst1[b], t = bst1[b + 1];
    int i = s + tid;
    for (; i + 256 < t; i += 512) {
      int pk0 = pkey[i], pk1 = pkey[i + 256];
      const float4* e0 = (const float4*)(edge_attr + (size_t)(pk0 >> 6) * FE);
      const float4* e1 = (const float4*)(edge_attr + (size_t)(pk1 >> 6) * FE);
      float4 a0 = e0[0], b0 = e0[1], a1 = e1[0], b1 = e1[1];
      int s0 = pk0 & 63, s1 = pk1 & 63;
      atomicAdd(&lds[0][s0], a0.x);  atomicAdd(&lds[1][s0], a0.y);
      atomicAdd(&lds[2][s0], a0.z);  atomicAdd(&lds[3][s0], a0.w);
      atomicAdd(&lds[4][s0], b0.x);  atomicAdd(&lds[5][s0], b0.y);
      atomicAdd(&lds[6][s0], b0.z);  atomicAdd(&lds[7][s0], b0.w);
      atomicAdd(&lds[0][s1], a1.x);  atomicAdd(&lds[1][s1], a1.y);
      atomicAdd(&lds[2][s1], a1.z);  atomicAdd(&lds[3][s1], a1.w);
      atomicAdd(&lds[4][s1], b1.x);  atomicAdd(&lds[5][s1], b1.y);
      atomicAdd(&lds[6][s1], b1.z);  atomicAdd(&lds[7][s1], b1.w);
    }
    for (; i < t; i += 256) {
      int pk = pkey[i];
      int e = pk >> 6, slot = pk & 63;
      const float4* ea = (const float4*)(edge_attr + (size_t)e * FE);
      float4 a = ea[0], b4 = ea[1];
      atomicAdd(&lds[0][slot], a.x);  atomicAdd(&lds[1][slot], a.y);
      atomicAdd(&lds[2][slot], a.z);  atomicAdd(&lds[3][slot], a.w);
      atomicAdd(&lds[4][slot], b4.x); atomicAdd(&lds[5][slot], b4.y);
      atomicAdd(&lds[6][slot], b4.z); atomicAdd(&lds[7][slot], b4.w);
    }
    __syncthreads();
    for (int pr = 0; pr < 32; pr++) {
      int nl = pr * 2 + half;
      int n = node0 + nl;
      float acc = bcol;
#pragma unroll
      for (int k = 0; k < FN; k++) acc += na[nl][k] * wreg[k];
#pragma unroll
      for (int k = 0; k < FE; k++) acc += lds[k][nl] * wreg[FN + k];
      if (n < N) hout[(size_t)n * H + col] = fmaxf(acc, 0.f);
    }
  } else {
    // ---- adjacency pass-2 path (emits offs, payF, rs) ----
    int b = blockIdx.x - nbuk;
    int s = bst2[b], t = bst2[b + 1];
    if (tid < 64) { cnt[tid] = 0; vsum[tid] = 0.f; }
    __syncthreads();
    for (int i = s + tid; i < t; i += 256) atomicAdd(&cnt[(bpay[i].x >> 20) & 63], 1);
    __syncthreads();
    if (tid < 64) scn[tid] = cnt[tid];
    __syncthreads();
    for (int off = 1; off < 64; off <<= 1) {
      int v = 0;
      if (tid < 64 && tid >= off) v = scn[tid - off];
      __syncthreads();
      if (tid < 64 && tid >= off) scn[tid] += v;
      __syncthreads();
    }
    if (tid < 64) {
      int excl = s + scn[tid] - cnt[tid];
      cur[tid] = excl;
      int node = b * 64 + tid;
      if (node < N) offs[node] = excl;
    }
    if (b == 0 && tid == 0) offs[N] = E;
    __syncthreads();
    for (int i = s + tid; i < t; i += 256) {
      int2 p = bpay[i];
      int slot = (p.x >> 20) & 63;
      int pos = atomicAdd(&cur[slot], 1);
      payF[pos] = make_int2(p.x & 0xFFFFF, p.y);
      atomicAdd(&vsum[slot], __int_as_float(p.y));
    }
    __syncthreads();
    if (tid < 64) {
      int node = b * 64 + tid;
      if (node < N) rs[node] = vsum[tid];
    }
  }
}

// ============================ fused GCN layer (round-0 structure: best measured) ============================
// out[n] = relu( (sum val*h[dst]) @ W + rs[n]*b ).  64-row tile, 32 KB LDS, 8 groups
// x 8 rows, acc[8], register gather (4-deep MLP), NO launch_bounds min-waves
// (forced caps spill: VGPR->32 + 16 MB scratch writes, rounds 1&2).
// Gather is pinned at ~2.5 TB/s on the L2-miss path regardless of occupancy
// (verified across 35/50/72% occupancy); duration tracks bytes 1:1.
__global__ __launch_bounds__(256) void k_fused(
    const float* __restrict__ h, const int* __restrict__ offs,
    const int2* __restrict__ pay, const float* __restrict__ W,
    const float* __restrict__ bias, const float* __restrict__ rs,
    float* __restrict__ out, int N) {
  __shared__ float4 hs4[64 * 32];   // 32 KB: [row][k4]
  int tid = threadIdx.x;
  int c  = tid & 31;
  int rg = tid >> 5;
  int base = blockIdx.x * 64;
  const float4* h4 = (const float4*)h;

  // ---- phase 1: group rg aggregates rows rg*8 .. rg*8+7 ----
  for (int r = 0; r < 8; r++) {
    int row = rg * 8 + r;
    int n = base + row;
    float4 a0 = make_float4(0.f, 0.f, 0.f, 0.f);
    float4 a1 = make_float4(0.f, 0.f, 0.f, 0.f);
    float4 a2 = make_float4(0.f, 0.f, 0.f, 0.f);
    float4 a3 = make_float4(0.f, 0.f, 0.f, 0.f);
    if (n < N) {
      int s = offs[n], t = offs[n + 1];
      int i = s, t4 = s + ((t - s) & ~3);
      for (; i < t4; i += 4) {
        int2 p0 = pay[i], p1 = pay[i + 1], p2 = pay[i + 2], p3 = pay[i + 3];
        float4 h0 = h4[(size_t)p0.x * 32 + c];
        float4 h1 = h4[(size_t)p1.x * 32 + c];
        float4 h2 = h4[(size_t)p2.x * 32 + c];
        float4 h3 = h4[(size_t)p3.x * 32 + c];
        float v0 = __int_as_float(p0.y), v1 = __int_as_float(p1.y);
        float v2 = __int_as_float(p2.y), v3 = __int_as_float(p3.y);
        a0.x += v0 * h0.x; a0.y += v0 * h0.y; a0.z += v0 * h0.z; a0.w += v0 * h0.w;
        a1.x += v1 * h1.x; a1.y += v1 * h1.y; a1.z += v1 * h1.z; a1.w += v1 * h1.w;
        a2.x += v2 * h2.x; a2.y += v2 * h2.y; a2.z += v2 * h2.z; a2.w += v2 * h2.w;
        a3.x += v3 * h3.x; a3.y += v3 * h3.y; a3.z += v3 * h3.z; a3.w += v3 * h3.w;
      }
      for (; i < t; i++) {
        int2 p = pay[i];
        float v = __int_as_float(p.y);
        float4 hv = h4[(size_t)p.x * 32 + c];
        a0.x += v * hv.x; a0.y += v * hv.y; a0.z += v * hv.z; a0.w += v * hv.w;
      }
    }
    hs4[row * 32 + c] = make_float4(a0.x + a1.x + a2.x + a3.x,
                                    a0.y + a1.y + a2.y + a3.y,
                                    a0.z + a1.z + a2.z + a3.z,
                                    a0.w + a1.w + a2.w + a3.w);
  }
  __syncthreads();

  // ---- phase 2: GEMM from LDS; W coalesced from global (L2-hot) ----
  const float4* W4 = (const float4*)W;   // [128][32]
  float4 acc[8];
#pragma unroll
  for (int i = 0; i < 8; i++) acc[i] = make_float4(0.f, 0.f, 0.f, 0.f);
#pragma unroll 2
  for (int k = 0; k < 32; k++) {
    float4 w0 = W4[(k * 4 + 0) * 32 + c];
    float4 w1 = W4[(k * 4 + 1) * 32 + c];
    float4 w2 = W4[(k * 4 + 2) * 32 + c];
    float4 w3 = W4[(k * 4 + 3) * 32 + c];
#pragma unroll
    for (int i = 0; i < 8; i++) {
      float4 hv = hs4[(rg + 8 * i) * 32 + k];   // wave-uniform broadcast
      acc[i].x += hv.x * w0.x + hv.y * w1.x + hv.z * w2.x + hv.w * w3.x;
      acc[i].y += hv.x * w0.y + hv.y * w1.y + hv.z * w2.y + hv.w * w3.y;
      acc[i].z += hv.x * w0.z + hv.y * w1.z + hv.z * w2.z + hv.w * w3.z;
      acc[i].w += hv.x * w0.w + hv.y * w1.w + hv.z * w2.w + hv.w * w3.w;
    }
  }

  float4 bv = ((const float4*)bias)[c];
#pragma unroll
  for (int i = 0; i < 8; i++) {
    int row = rg + 8 * i;
    int n = base + row;
    if (n < N) {
      float rsv = rs[n];
      float4 o;
      o.x = fmaxf(acc[i].x + rsv * bv.x, 0.f);
      o.y = fmaxf(acc[i].y + rsv * bv.y, 0.f);
      o.z = fmaxf(acc[i].z + rsv * bv.z, 0.f);
      o.w = fmaxf(acc[i].w + rsv * bv.w, 0.f);
      ((float4*)out)[(size_t)n * 32 + c] = o;
    }
  }
}

// ============================ layer-3 variant: pool fused, no global h write ============================
// Layer-3 output feeds ONLY global_add_pool -> stash relu result in hs4 (free
// after phase-2), segment-reduce by batch[] in LDS (batch sorted: block spans
// ~2 graphs), one atomicAdd per (graph, feature) per block. Deletes the 50 MB
// layer-3 write + 51 MB pool read + the k_pool_seg/gstart machinery.
__global__ __launch_bounds__(256) void k_fused_pool(
    const float* __restrict__ h, const int* __restrict__ offs,
    const int2* __restrict__ pay, const float* __restrict__ W,
    const float* __restrict__ bias, const float* __restrict__ rs,
    const int* __restrict__ batch, float* __restrict__ fpool, int N) {
  __shared__ float4 hs4[64 * 32];   // 32 KB
  __shared__ float4 psum[8][32];    // 4 KB
  __shared__ int btl[64];
  int tid = threadIdx.x;
  int c  = tid & 31;
  int rg = tid >> 5;
  int base = blockIdx.x * 64;
  const float4* h4 = (const float4*)h;
  if (tid < 64) btl[tid] = (base + tid < N) ? batch[base + tid] : -1;

  // ---- phase 1: identical gather ----
  for (int r = 0; r < 8; r++) {
    int row = rg * 8 + r;
    int n = base + row;
    float4 a0 = make_float4(0.f, 0.f, 0.f, 0.f);
    float4 a1 = make_float4(0.f, 0.f, 0.f, 0.f);
    float4 a2 = make_float4(0.f, 0.f, 0.f, 0.f);
    float4 a3 = make_float4(0.f, 0.f, 0.f, 0.f);
    if (n < N) {
      int s = offs[n], t = offs[n + 1];
      int i = s, t4 = s + ((t - s) & ~3);
      for (; i < t4; i += 4) {
        int2 p0 = pay[i], p1 = pay[i + 1], p2 = pay[i + 2], p3 = pay[i + 3];
        float4 h0 = h4[(size_t)p0.x * 32 + c];
        float4 h1 = h4[(size_t)p1.x * 32 + c];
        float4 h2 = h4[(size_t)p2.x * 32 + c];
        float4 h3 = h4[(size_t)p3.x * 32 + c];
        float v0 = __int_as_float(p0.y), v1 = __int_as_float(p1.y);
        float v2 = __int_as_float(p2.y), v3 = __int_as_float(p3.y);
        a0.x += v0 * h0.x; a0.y += v0 * h0.y; a0.z += v0 * h0.z; a0.w += v0 * h0.w;
        a1.x += v1 * h1.x; a1.y += v1 * h1.y; a1.z += v1 * h1.z; a1.w += v1 * h1.w;
        a2.x += v2 * h2.x; a2.y += v2 * h2.y; a2.z += v2 * h2.z; a2.w += v2 * h2.w;
        a3.x += v3 * h3.x; a3.y += v3 * h3.y; a3.z += v3 * h3.z; a3.w += v3 * h3.w;
      }
      for (; i < t; i++) {
        int2 p = pay[i];
        float v = __int_as_float(p.y);
        float4 hv = h4[(size_t)p.x * 32 + c];
        a0.x += v * hv.x; a0.y += v * hv.y; a0.z += v * hv.z; a0.w += v * hv.w;
      }
    }
    hs4[row * 32 + c] = make_float4(a0.x + a1.x + a2.x + a3.x,
                                    a0.y + a1.y + a2.y + a3.y,
                                    a0.z + a1.z + a2.z + a3.z,
                                    a0.w + a1.w + a2.w + a3.w);
  }
  __syncthreads();

  // ---- phase 2: identical GEMM ----
  const float4* W4 = (const float4*)W;
  float4 acc[8];
#pragma unroll
  for (int i = 0; i < 8; i++) acc[i] = make_float4(0.f, 0.f, 0.f, 0.f);
#pragma unroll 2
  for (int k = 0; k < 32; k++) {
    float4 w0 = W4[(k * 4 + 0) * 32 + c];
    float4 w1 = W4[(k * 4 + 1) * 32 + c];
    float4 w2 = W4[(k * 4 + 2) * 32 + c];
    float4 w3 = W4[(k * 4 + 3) * 32 + c];
#pragma unroll
    for (int i = 0; i < 8; i++) {
      float4 hv = hs4[(rg + 8 * i) * 32 + k];
      acc[i].x += hv.x * w0.x + hv.y * w1.x + hv.z * w2.x + hv.w * w3.x;
      acc[i].y += hv.x * w0.y + hv.y * w1.y + hv.z * w2.y + hv.w * w3.y;
      acc[i].z += hv.x * w0.z + hv.y * w1.z + hv.z * w2.z + hv.w * w3.z;
      acc[i].w += hv.x * w0.w + hv.y * w1.w + hv.z * w2.w + hv.w * w3.w;
    }
  }

  // ---- epilogue: relu -> hs4 (all phase-2 reads done), then pool by graph ----
  float4 bv = ((const float4*)bias)[c];
  __syncthreads();
#pragma unroll
  for (int i = 0; i < 8; i++) {
    int row = rg + 8 * i;
    int n = base + row;
    float4 o = make_float4(0.f, 0.f, 0.f, 0.f);
    if (n < N) {
      float rsv = rs[n];
      o.x = fmaxf(acc[i].x + rsv * bv.x, 0.f);
      o.y = fmaxf(acc[i].y + rsv * bv.y, 0.f);
      o.z = fmaxf(acc[i].z + rsv * bv.z, 0.f);
      o.w = fmaxf(acc[i].w + rsv * bv.w, 0.f);
    }
    hs4[row * 32 + c] = o;
  }
  __syncthreads();

  int g0 = btl[0];
  int g1 = g0;
  for (int r = 1; r < 64; r++) { int bb = btl[r]; if (bb >= 0) g1 = bb; }  // nondecreasing
  for (int gr = g0; gr <= g1; gr++) {
    float4 s = make_float4(0.f, 0.f, 0.f, 0.f);
#pragma unroll
    for (int r = rg * 8; r < rg * 8 + 8; r++) {
      if (btl[r] == gr) {
        float4 v = hs4[r * 32 + c];
        s.x += v.x; s.y += v.y; s.z += v.z; s.w += v.w;
      }
    }
    psum[rg][c] = s;
    __syncthreads();
    if (rg == 0) {
      float4 tot = psum[0][c];
#pragma unroll
      for (int j = 1; j < 8; j++) {
        float4 v = psum[j][c];
        tot.x += v.x; tot.y += v.y; tot.z += v.z; tot.w += v.w;
      }
      float* dst = fpool + (size_t)gr * H + c * 4;
      atomicAdd(dst + 0, tot.x);
      atomicAdd(dst + 1, tot.y);
      atomicAdd(dst + 2, tot.z);
      atomicAdd(dst + 3, tot.w);
    }
    __syncthreads();
  }
}

// ============================ predictor GEMM with fused final dot ============================
__global__ __launch_bounds__(256) void k_gemm_pred(
    const float* __restrict__ in, const float* __restrict__ W,
    const float* __restrict__ bias, const float* __restrict__ Wp2,
    const float* __restrict__ bp2, float* __restrict__ out, int N) {
  __shared__ float4 hs4[64 * 32];
  int tid = threadIdx.x;
  int c  = tid & 31;
  int rg = tid >> 5;
  int rowBase = blockIdx.x * 64;
  const float4* in4 = (const float4*)in;
  const float4* W4  = (const float4*)W;
#pragma unroll
  for (int j = 0; j < 8; j++) {
    int q = tid + 256 * j;
    int r = rowBase + (q >> 5);
    int rr = (r < N) ? r : (N - 1);
    hs4[q] = in4[(size_t)rr * 32 + (q & 31)];
  }
  __syncthreads();
  float4 acc[8];
#pragma unroll
  for (int i = 0; i < 8; i++) acc[i] = make_float4(0.f, 0.f, 0.f, 0.f);
#pragma unroll 2
  for (int k = 0; k < 32; k++) {
    float4 w0 = W4[(k * 4 + 0) * 32 + c];
    float4 w1 = W4[(k * 4 + 1) * 32 + c];
    float4 w2 = W4[(k * 4 + 2) * 32 + c];
    float4 w3 = W4[(k * 4 + 3) * 32 + c];
#pragma unroll
    for (int i = 0; i < 8; i++) {
      float4 hv = hs4[(rg + 8 * i) * 32 + k];
      acc[i].x += hv.x * w0.x + hv.y * w1.x + hv.z * w2.x + hv.w * w3.x;
      acc[i].y += hv.x * w0.y + hv.y * w1.y + hv.z * w2.y + hv.w * w3.y;
      acc[i].z += hv.x * w0.z + hv.y * w1.z + hv.z * w2.z + hv.w * w3.z;
      acc[i].w += hv.x * w0.w + hv.y * w1.w + hv.z * w2.w + hv.w * w3.w;
    }
  }
  float4 bv = ((const float4*)bias)[c];
  float4 wp = ((const float4*)Wp2)[c];
  float bp = bp2[0];
#pragma unroll
  for (int i = 0; i < 8; i++) {
    int row = rowBase + rg + 8 * i;
    float4 o;
    o.x = fmaxf(acc[i].x + bv.x, 0.f);
    o.y = fmaxf(acc[i].y + bv.y, 0.f);
    o.z = fmaxf(acc[i].z + bv.z, 0.f);
    o.w = fmaxf(acc[i].w + bv.w, 0.f);
    float v = o.x * wp.x + o.y * wp.y + o.z * wp.z + o.w * wp.w;
#pragma unroll
    for (int off = 16; off > 0; off >>= 1) v += __shfl_down(v, off, 32);
    if (c == 0 && row < N) out[row] = v + bp;
  }
}

// ============================ launch ============================
extern "C" void kernel_launch(void* const* d_in, const int* in_sizes, int n_in,
                              void* d_out, int out_size, void* d_ws, size_t ws_size,
                              hipStream_t stream) {
  const float* node_attr  = (const float*)d_in[0];
  const float* edge_attr  = (const float*)d_in[1];
  const int*   edge_index = (const int*)d_in[2];
  const int*   adj_index  = (const int*)d_in[3];
  const float* adj_value  = (const float*)d_in[4];
  const int*   batch      = (const int*)d_in[5];
  const float* W_node  = (const float*)d_in[6];
  const float* W_edge  = (const float*)d_in[7];
  const float* b_embed = (const float*)d_in[8];
  const float* W1 = (const float*)d_in[9];
  const float* b1 = (const float*)d_in[10];
  const float* W2 = (const float*)d_in[11];
  const float* b2 = (const float*)d_in[12];
  const float* W3 = (const float*)d_in[13];
  const float* b3 = (const float*)d_in[14];
  const float* Wp1 = (const float*)d_in[15];
  const float* bp1 = (const float*)d_in[16];
  const float* Wp2 = (const float*)d_in[17];
  const float* bp2 = (const float*)d_in[18];
  float* out = (float*)d_out;

  const int E = in_sizes[4];           // 1,600,000
  const int N = in_sizes[5];           // 100,000
  const int G = out_size;              // 2048
  const int nbuk = (N + 63) >> 6;      // 1563
  const int p1b = (E + 8191) / 8192;

  // ---- workspace layout ----
  float* A     = (float*)d_ws;                       // N*H
  float* B     = A + (size_t)N * H;                  // N*H
  int2*  payF  = (int2*)(B + (size_t)N * H);         // E
  float* fpool = (float*)(payF + E);                 // G*H   } one memset
  int*   bcnt1 = (int*)(fpool + (size_t)G * H);      // nbuk  } (fpool zeroed for
  int*   bcnt2 = bcnt1 + nbuk;                       // nbuk  }  pool atomics)
  int*   bst1  = bcnt2 + nbuk;                       // nbuk+1
  int*   gcur1 = bst1 + nbuk + 1;                    // nbuk
  int*   bst2  = gcur1 + nbuk;                       // nbuk+1
  int*   gcur2 = bst2 + nbuk + 1;                    // nbuk
  int*   offs2 = gcur2 + nbuk;                       // N+1
  float* rs    = (float*)(offs2 + N + 1);            // N
  // transient aliases (lifetimes by launch order):
  int*   pkey  = (int*)B;                            // E ints; dead after agg_p2
  int2*  bpay2 = (int2*)(((int*)B) + E);             // E int2; dead after agg_p2
  // h lives in A (agg_p2 reads pkey/bpay2 from B while writing h -> must not alias B)

  // ---- zero fpool + histogram counters in one memset; histograms + scans ----
  hipMemsetAsync(fpool, 0, (size_t)G * H * sizeof(float) + 2 * nbuk * sizeof(int), stream);
  k_hist2<<<512, 256, 0, stream>>>(edge_index + E, adj_index, bcnt1, bcnt2, E, nbuk);
  k_scan<<<1, 1024, 0, stream>>>(bcnt1, bst1, gcur1, bcnt2, bst2, gcur2, nbuk);

  // ---- both pass-1 scatters in one launch ----
  k_p1_both<<<2 * p1b, 256, 0, stream>>>(edge_index + E, adj_index, adj_value,
                                         gcur1, gcur2, pkey, bpay2, E, nbuk, p1b);

  // ---- embed agg + h compute | adj pass-2, one launch; h -> A ----
  k_agg_p2<<<2 * nbuk, 256, 0, stream>>>(pkey, edge_attr, bst1,
                                         node_attr, W_node, W_edge, b_embed, A,
                                         bpay2, bst2, offs2, payF, rs, N, E, nbuk);

  // ---- 3 fused GCN layers; layer 3 pools directly into fpool ----
  int lb = (N + 63) / 64;
  k_fused<<<lb, 256, 0, stream>>>(A, offs2, payF, W1, b1, rs, B, N);
  k_fused<<<lb, 256, 0, stream>>>(B, offs2, payF, W2, b2, rs, A, N);
  k_fused_pool<<<lb, 256, 0, stream>>>(A, offs2, payF, W3, b3, rs, batch, fpool, N);

  // ---- predictor (final dot fused into the GEMM) ----
  k_gemm_pred<<<(G + 63) / 64, 256, 0, stream>>>(fpool, Wp1, bp1, Wp2, bp2, out, G);
}